// Round 1
// baseline (330.181 us; speedup 1.0000x reference)
//
#include <hip/hip_runtime.h>
#include <hip/hip_bf16.h>

// Problem constants
#define BATCH 16
#define NNODE 2048
#define NEDGE 65536
#define DIN   256
#define DOUT  256
#define KDIM  512   // 2*DIN

// ---------------------------------------------------------------------------
// Kernel 1: count in-degree per (batch, dst)
// ---------------------------------------------------------------------------
__global__ void count_kernel(const int* __restrict__ edges, int* __restrict__ counts) {
    int idx = blockIdx.x * blockDim.x + threadIdx.x;   // 0 .. B*E-1
    int b = idx >> 16;            // / NEDGE
    int e = idx & (NEDGE - 1);
    int dst = edges[(size_t)b * 2 * NEDGE + NEDGE + e];
    atomicAdd(&counts[b * NNODE + dst], 1);
}

// ---------------------------------------------------------------------------
// Kernel 2: per-batch exclusive scan of counts -> offsets (and cursor copy)
// one block (256 threads) per batch; N=2048 -> 8 elements/thread
// ---------------------------------------------------------------------------
__global__ void scan_kernel(const int* __restrict__ counts,
                            int* __restrict__ offsets,
                            int* __restrict__ cursor) {
    __shared__ int tsums[256];
    int b = blockIdx.x;
    int t = threadIdx.x;
    const int base = b * NNODE;
    int local[8];
    int s = 0;
#pragma unroll
    for (int j = 0; j < 8; ++j) { local[j] = counts[base + t * 8 + j]; s += local[j]; }
    tsums[t] = s;
    __syncthreads();
    // Hillis-Steele inclusive scan over 256 thread sums
    for (int off = 1; off < 256; off <<= 1) {
        int v = (t >= off) ? tsums[t - off] : 0;
        __syncthreads();
        tsums[t] += v;
        __syncthreads();
    }
    int run = (t == 0) ? 0 : tsums[t - 1];
#pragma unroll
    for (int j = 0; j < 8; ++j) {
        offsets[base + t * 8 + j] = run;
        cursor[base + t * 8 + j]  = run;
        run += local[j];
    }
}

// ---------------------------------------------------------------------------
// Kernel 3: fill CSR src-index lists (counting sort by dst)
// ---------------------------------------------------------------------------
__global__ void fill_kernel(const int* __restrict__ edges,
                            int* __restrict__ cursor,
                            int* __restrict__ srcIdx) {
    int idx = blockIdx.x * blockDim.x + threadIdx.x;   // 0 .. B*E-1
    int b = idx >> 16;
    int e = idx & (NEDGE - 1);
    int src = edges[(size_t)b * 2 * NEDGE + e];
    int dst = edges[(size_t)b * 2 * NEDGE + NEDGE + e];
    int pos = atomicAdd(&cursor[b * NNODE + dst], 1);
    srcIdx[(size_t)b * NEDGE + pos] = src;
}

// ---------------------------------------------------------------------------
// Kernel 4: pull-style neighbor mean. One wave (64 lanes) per node; each lane
// owns 4 contiguous features (float4). No float atomics.
// ---------------------------------------------------------------------------
__global__ __launch_bounds__(256) void aggregate_kernel(
        const float* __restrict__ X,
        const int* __restrict__ srcIdx,
        const int* __restrict__ offsets,
        const int* __restrict__ counts,
        float* __restrict__ agg) {
    int wave = threadIdx.x >> 6;             // 0..3
    int lane = threadIdx.x & 63;
    int node = blockIdx.x * 4 + wave;        // 0 .. B*N-1
    int b = node >> 11;                      // / NNODE
    int start = offsets[node];
    int deg   = counts[node];
    const float* xb  = X + (size_t)b * NNODE * DIN;
    const int* sidx  = srcIdx + (size_t)b * NEDGE + start;
    int d0 = lane * 4;
    float4 acc = {0.f, 0.f, 0.f, 0.f};
    for (int i = 0; i < deg; ++i) {
        int s = sidx[i];
        const float4 v = *reinterpret_cast<const float4*>(xb + (size_t)s * DIN + d0);
        acc.x += v.x; acc.y += v.y; acc.z += v.z; acc.w += v.w;
    }
    float scale = 1.0f / (float)max(deg, 1);
    float4 o = {acc.x * scale, acc.y * scale, acc.z * scale, acc.w * scale};
    *reinterpret_cast<float4*>(agg + (size_t)node * DIN + d0) = o;
}

// ---------------------------------------------------------------------------
// Kernel 5: fp32 GEMM  out[r][o] = sum_k combined[r][k] * W[o][k] + bias[o]
// combined[r][0:256] = X row r, combined[r][256:512] = agg row r.
// Tiling: BM=64, BN=64, BK=16; 256 threads; 4x4 per thread; float4 LDS reads.
// ---------------------------------------------------------------------------
#define BM 64
#define BN 64
#define BK 16
__global__ __launch_bounds__(256) void gemm_kernel(
        const float* __restrict__ X,
        const float* __restrict__ agg,
        const float* __restrict__ W,
        const float* __restrict__ bias,
        float* __restrict__ out) {
    __shared__ float As[BK][BM];
    __shared__ float Bs[BK][BN];
    int tid = threadIdx.x;
    int rowBase = blockIdx.x * BM;           // over B*N
    int colBase = blockIdx.y * BN;           // over DOUT
    int tx = tid & 15, ty = tid >> 4;        // 16 x 16 thread grid
    int lrow = tid & 63;                     // loader row 0..63
    int lk4  = (tid >> 6) * 4;               // loader k-quad 0,4,8,12

    float acc[4][4] = {};

    for (int k0 = 0; k0 < KDIM; k0 += BK) {
        int kk = k0 + lk4;
        const float* srcA = (kk < DIN)
            ? (X   + (size_t)(rowBase + lrow) * DIN + kk)
            : (agg + (size_t)(rowBase + lrow) * DIN + (kk - DIN));
        float4 a = *reinterpret_cast<const float4*>(srcA);
        As[lk4 + 0][lrow] = a.x; As[lk4 + 1][lrow] = a.y;
        As[lk4 + 2][lrow] = a.z; As[lk4 + 3][lrow] = a.w;

        float4 w = *reinterpret_cast<const float4*>(
            W + (size_t)(colBase + lrow) * KDIM + kk);
        Bs[lk4 + 0][lrow] = w.x; Bs[lk4 + 1][lrow] = w.y;
        Bs[lk4 + 2][lrow] = w.z; Bs[lk4 + 3][lrow] = w.w;
        __syncthreads();
#pragma unroll
        for (int k = 0; k < BK; ++k) {
            float4 av = *reinterpret_cast<const float4*>(&As[k][ty * 4]);
            float4 bv = *reinterpret_cast<const float4*>(&Bs[k][tx * 4]);
            float a4[4] = {av.x, av.y, av.z, av.w};
            float b4[4] = {bv.x, bv.y, bv.z, bv.w};
#pragma unroll
            for (int i = 0; i < 4; ++i)
#pragma unroll
                for (int j = 0; j < 4; ++j)
                    acc[i][j] += a4[i] * b4[j];
        }
        __syncthreads();
    }

    float b0 = bias[colBase + tx * 4 + 0];
    float b1 = bias[colBase + tx * 4 + 1];
    float b2 = bias[colBase + tx * 4 + 2];
    float b3 = bias[colBase + tx * 4 + 3];
#pragma unroll
    for (int i = 0; i < 4; ++i) {
        int r = rowBase + ty * 4 + i;
        float4 o;
        o.x = acc[i][0] + b0;
        o.y = acc[i][1] + b1;
        o.z = acc[i][2] + b2;
        o.w = acc[i][3] + b3;
        *reinterpret_cast<float4*>(out + (size_t)r * DOUT + colBase + tx * 4) = o;
    }
}

// ---------------------------------------------------------------------------
extern "C" void kernel_launch(void* const* d_in, const int* in_sizes, int n_in,
                              void* d_out, int out_size, void* d_ws, size_t ws_size,
                              hipStream_t stream) {
    const float* X    = (const float*)d_in[0];   // (B, N, DIN)
    const int*   E    = (const int*)d_in[1];     // (B, 2, NEDGE) int32
    const float* W    = (const float*)d_in[2];   // (DOUT, 2*DIN)
    const float* bias = (const float*)d_in[3];   // (DOUT,)
    float* out = (float*)d_out;                  // (B, N, DOUT)

    // Workspace layout (floats first for alignment)
    char* ws = (char*)d_ws;
    float* agg     = (float*)ws;                                   // B*N*DIN floats = 33.5 MB
    size_t aggB    = (size_t)BATCH * NNODE * DIN * sizeof(float);
    int* counts    = (int*)(ws + aggB);                            // B*N ints
    int* offsets   = counts + BATCH * NNODE;
    int* cursor    = offsets + BATCH * NNODE;
    int* srcIdx    = cursor + BATCH * NNODE;                       // B*E ints = 4 MB

    // zero the counts (only buffer that is accumulated into)
    hipMemsetAsync(counts, 0, (size_t)BATCH * NNODE * sizeof(int), stream);

    const int totalE = BATCH * NEDGE;            // 1,048,576
    count_kernel<<<totalE / 256, 256, 0, stream>>>(E, counts);
    scan_kernel<<<BATCH, 256, 0, stream>>>(counts, offsets, cursor);
    fill_kernel<<<totalE / 256, 256, 0, stream>>>(E, cursor, srcIdx);

    aggregate_kernel<<<(BATCH * NNODE) / 4, 256, 0, stream>>>(X, srcIdx, offsets, counts, agg);

    dim3 ggrid((BATCH * NNODE) / BM, DOUT / BN);
    gemm_kernel<<<ggrid, 256, 0, stream>>>(X, agg, W, bias, out);
}

// Round 2
// 192.770 us; speedup vs baseline: 1.7128x; 1.7128x over previous
//
#include <hip/hip_runtime.h>
#include <hip/hip_bf16.h>

#define BATCH 16
#define NNODE 2048
#define NEDGE 65536
#define DIN   256
#define DOUT  256
#define KDIM  512   // 2*DIN

typedef __attribute__((ext_vector_type(8))) short short8;
typedef __attribute__((ext_vector_type(4))) float f32x4;

__device__ __forceinline__ ushort f2bf(float f) {
    union { float f; unsigned u; } v; v.f = f;
    unsigned u = v.u;
    unsigned r = (u + 0x7fffu + ((u >> 16) & 1u)) >> 16;  // RNE
    return (ushort)r;
}
__device__ __forceinline__ float bf2f(ushort h) {
    union { unsigned u; float f; } v; v.u = ((unsigned)h) << 16;
    return v.f;
}

#define ASYNC_COPY16(gsrc, ldst) \
    __builtin_amdgcn_global_load_lds((const __attribute__((address_space(1))) void*)(gsrc), \
                                     (__attribute__((address_space(3))) void*)(ldst), 16, 0, 0)

// ---------------------------------------------------------------------------
// fp32 -> bf16 conversion, 8 elements per thread
// ---------------------------------------------------------------------------
__global__ void convert_kernel(const float* __restrict__ in, ushort* __restrict__ out, int n8) {
    int i = blockIdx.x * blockDim.x + threadIdx.x;
    if (i >= n8) return;
    const float4* p = reinterpret_cast<const float4*>(in + (size_t)i * 8);
    float4 u = p[0], v = p[1];
    ushort4 o0 = { f2bf(u.x), f2bf(u.y), f2bf(u.z), f2bf(u.w) };
    ushort4 o1 = { f2bf(v.x), f2bf(v.y), f2bf(v.z), f2bf(v.w) };
    *reinterpret_cast<ushort4*>(out + (size_t)i * 8)     = o0;
    *reinterpret_cast<ushort4*>(out + (size_t)i * 8 + 4) = o1;
}

// ---------------------------------------------------------------------------
// Kernel 1: count in-degree per (batch, dst)
// ---------------------------------------------------------------------------
__global__ void count_kernel(const int* __restrict__ edges, int* __restrict__ counts) {
    int idx = blockIdx.x * blockDim.x + threadIdx.x;   // 0 .. B*E-1
    int b = idx >> 16;
    int e = idx & (NEDGE - 1);
    int dst = edges[(size_t)b * 2 * NEDGE + NEDGE + e];
    atomicAdd(&counts[b * NNODE + dst], 1);
}

// ---------------------------------------------------------------------------
// Kernel 2: per-batch exclusive scan of counts -> cursor
// ---------------------------------------------------------------------------
__global__ void scan_kernel(const int* __restrict__ counts, int* __restrict__ cursor) {
    __shared__ int tsums[256];
    int b = blockIdx.x;
    int t = threadIdx.x;
    const int base = b * NNODE;
    int local[8];
    int s = 0;
#pragma unroll
    for (int j = 0; j < 8; ++j) { local[j] = counts[base + t * 8 + j]; s += local[j]; }
    tsums[t] = s;
    __syncthreads();
    for (int off = 1; off < 256; off <<= 1) {
        int v = (t >= off) ? tsums[t - off] : 0;
        __syncthreads();
        tsums[t] += v;
        __syncthreads();
    }
    int run = (t == 0) ? 0 : tsums[t - 1];
#pragma unroll
    for (int j = 0; j < 8; ++j) {
        cursor[base + t * 8 + j] = run;
        run += local[j];
    }
}

// ---------------------------------------------------------------------------
// Kernel 3: fill CSR src-index lists (counting sort by dst)
// ---------------------------------------------------------------------------
__global__ void fill_kernel(const int* __restrict__ edges,
                            int* __restrict__ cursor,
                            int* __restrict__ srcIdx) {
    int idx = blockIdx.x * blockDim.x + threadIdx.x;
    int b = idx >> 16;
    int e = idx & (NEDGE - 1);
    int src = edges[(size_t)b * 2 * NEDGE + e];
    int dst = edges[(size_t)b * 2 * NEDGE + NEDGE + e];
    int pos = atomicAdd(&cursor[b * NNODE + dst], 1);
    srcIdx[(size_t)b * NEDGE + pos] = src;
}

// ---------------------------------------------------------------------------
// Kernel 4: pull-style neighbor mean over bf16 features, fp32 accumulate,
// bf16 output. One wave per node; lane owns 4 features (8B loads).
// XCD swizzle: blocks of the same 2 batches land on the same XCD -> gathers
// hit XCD-local L2 (2 MB working set < 4 MB L2).
// ---------------------------------------------------------------------------
__global__ __launch_bounds__(256) void aggregate_kernel(
        const ushort* __restrict__ Xbf,
        const int* __restrict__ srcIdx,
        const int* __restrict__ cursor,
        const int* __restrict__ counts,
        ushort* __restrict__ Gbf) {
    int bid = blockIdx.x;                     // 8192 blocks
    int blk = (bid & 7) * 1024 + (bid >> 3);  // XCD-contiguous remap (bijective)
    int wave = threadIdx.x >> 6;
    int lane = threadIdx.x & 63;
    int node = blk * 4 + wave;                // 0 .. B*N-1
    int b = node >> 11;
    int deg = counts[node];
    int start = cursor[node] - deg;           // cursor is end-offset after fill
    const ushort* xb = Xbf + (size_t)b * NNODE * DIN;
    const int* sidx = srcIdx + (size_t)b * NEDGE + start;
    int d0 = lane * 4;
    float a0 = 0.f, a1 = 0.f, a2 = 0.f, a3 = 0.f;
    int i = 0;
    for (; i + 2 <= deg; i += 2) {
        int s0 = sidx[i], s1 = sidx[i + 1];
        ushort4 v0 = *reinterpret_cast<const ushort4*>(xb + (size_t)s0 * DIN + d0);
        ushort4 v1 = *reinterpret_cast<const ushort4*>(xb + (size_t)s1 * DIN + d0);
        a0 += bf2f(v0.x) + bf2f(v1.x);
        a1 += bf2f(v0.y) + bf2f(v1.y);
        a2 += bf2f(v0.z) + bf2f(v1.z);
        a3 += bf2f(v0.w) + bf2f(v1.w);
    }
    if (i < deg) {
        int s0 = sidx[i];
        ushort4 v0 = *reinterpret_cast<const ushort4*>(xb + (size_t)s0 * DIN + d0);
        a0 += bf2f(v0.x); a1 += bf2f(v0.y); a2 += bf2f(v0.z); a3 += bf2f(v0.w);
    }
    float sc = 1.0f / (float)max(deg, 1);
    ushort4 o = { f2bf(a0 * sc), f2bf(a1 * sc), f2bf(a2 * sc), f2bf(a3 * sc) };
    *reinterpret_cast<ushort4*>(Gbf + (size_t)node * DIN + d0) = o;
}

// ---------------------------------------------------------------------------
// Kernel 5: bf16 MFMA GEMM (m97 structure).
//   out[r][o] = sum_k combined[r][k] * W[o][k] + bias[o]
//   combined row = [Xbf row | Gbf row], K = 512. Tile 128x128, BK=32,
//   4 waves (2x2), each wave 64x64 via 4x4 x mfma_f32_16x16x32_bf16.
//   Staging via global_load_lds width 16 into linear LDS.
// ---------------------------------------------------------------------------
__global__ __launch_bounds__(256) void gemm_kernel(
        const ushort* __restrict__ Xbf,
        const ushort* __restrict__ Gbf,
        const ushort* __restrict__ Wbf,
        const float* __restrict__ bias,
        float* __restrict__ out) {
    __shared__ ushort As[128 * 32];   // [row][k] 32 k per row
    __shared__ ushort Bs[128 * 32];   // [col][k]
    const int tid = threadIdx.x;
    const int wid = tid >> 6, lane = tid & 63;
    const int rowBase = blockIdx.x * 128;   // over B*N
    const int colBase = blockIdx.y * 128;   // over DOUT
    const int wm = wid >> 1, wn = wid & 1;

    f32x4 acc[4][4] = {};

    const int lr = lane >> 2;          // 0..15 row-within-slab
    const int lk = (lane & 3) * 8;     // k element slot

    for (int k0 = 0; k0 < KDIM; k0 += 32) {
        const ushort* Ab = (k0 < DIN)
            ? (Xbf + (size_t)rowBase * DIN + k0)
            : (Gbf + (size_t)rowBase * DIN + (k0 - DIN));
        const ushort* Bb = Wbf + (size_t)colBase * KDIM + k0;
        int r0 = wid * 16 + lr;
        ASYNC_COPY16(Ab + (size_t)r0 * DIN + lk,        &As[wid * 512]);
        ASYNC_COPY16(Ab + (size_t)(r0 + 64) * DIN + lk, &As[2048 + wid * 512]);
        ASYNC_COPY16(Bb + (size_t)r0 * KDIM + lk,       &Bs[wid * 512]);
        ASYNC_COPY16(Bb + (size_t)(r0 + 64) * KDIM + lk,&Bs[2048 + wid * 512]);
        __syncthreads();

        short8 a[4], b[4];
#pragma unroll
        for (int m = 0; m < 4; ++m)
            a[m] = *reinterpret_cast<const short8*>(
                &As[(wm * 64 + m * 16 + (lane & 15)) * 32 + (lane >> 4) * 8]);
#pragma unroll
        for (int n = 0; n < 4; ++n)
            b[n] = *reinterpret_cast<const short8*>(
                &Bs[(wn * 64 + n * 16 + (lane & 15)) * 32 + (lane >> 4) * 8]);
#pragma unroll
        for (int m = 0; m < 4; ++m)
#pragma unroll
            for (int n = 0; n < 4; ++n)
                acc[m][n] = __builtin_amdgcn_mfma_f32_16x16x32_bf16(
                    a[m], b[n], acc[m][n], 0, 0, 0);
        __syncthreads();
    }

    // epilogue: C/D layout col=lane&15, row=(lane>>4)*4+reg (m89-verified)
    const int cl = lane & 15, rq = lane >> 4;
#pragma unroll
    for (int n = 0; n < 4; ++n) {
        int col = colBase + wn * 64 + n * 16 + cl;
        float bv = bias[col];
#pragma unroll
        for (int m = 0; m < 4; ++m) {
            int r0 = rowBase + wm * 64 + m * 16 + rq * 4;
#pragma unroll
            for (int j = 0; j < 4; ++j)
                out[(size_t)(r0 + j) * DOUT + col] = acc[m][n][j] + bv;
        }
    }
}

// ---------------------------------------------------------------------------
extern "C" void kernel_launch(void* const* d_in, const int* in_sizes, int n_in,
                              void* d_out, int out_size, void* d_ws, size_t ws_size,
                              hipStream_t stream) {
    const float* X    = (const float*)d_in[0];   // (B, N, DIN)
    const int*   E    = (const int*)d_in[1];     // (B, 2, NEDGE) int32
    const float* W    = (const float*)d_in[2];   // (DOUT, KDIM)
    const float* bias = (const float*)d_in[3];   // (DOUT,)
    float* out = (float*)d_out;                  // (B, N, DOUT)

    char* ws = (char*)d_ws;
    ushort* Xbf = (ushort*)ws;                                  // 16.78 MB
    ushort* Gbf = Xbf + (size_t)BATCH * NNODE * DIN;            // 16.78 MB
    ushort* Wbf = Gbf + (size_t)BATCH * NNODE * DIN;            // 256 KB
    int* counts = (int*)(Wbf + (size_t)DOUT * KDIM);            // 128 KB
    int* cursor = counts + BATCH * NNODE;                       // 128 KB
    int* srcIdx = cursor + BATCH * NNODE;                       // 4 MB

    hipMemsetAsync(counts, 0, (size_t)BATCH * NNODE * sizeof(int), stream);

    convert_kernel<<<(BATCH * NNODE * DIN / 8) / 256, 256, 0, stream>>>(
        X, Xbf, BATCH * NNODE * DIN / 8);
    convert_kernel<<<(DOUT * KDIM / 8) / 256, 256, 0, stream>>>(
        W, Wbf, DOUT * KDIM / 8);

    const int totalE = BATCH * NEDGE;
    count_kernel<<<totalE / 256, 256, 0, stream>>>(E, counts);
    scan_kernel<<<BATCH, 256, 0, stream>>>(counts, cursor);
    fill_kernel<<<totalE / 256, 256, 0, stream>>>(E, cursor, srcIdx);

    aggregate_kernel<<<(BATCH * NNODE) / 4, 256, 0, stream>>>(
        Xbf, srcIdx, cursor, counts, Gbf);

    dim3 ggrid((BATCH * NNODE) / 128, DOUT / 128);
    gemm_kernel<<<ggrid, 256, 0, stream>>>(Xbf, Gbf, Wbf, bias, out);
}

// Round 3
// 142.324 us; speedup vs baseline: 2.3199x; 1.3544x over previous
//
#include <hip/hip_runtime.h>
#include <hip/hip_bf16.h>

#define BATCH 16
#define NNODE 2048
#define NEDGE 65536
#define DIN   256
#define DOUT  256
#define KDIM  512   // 2*DIN

typedef __attribute__((ext_vector_type(8))) short short8;
typedef __attribute__((ext_vector_type(8))) ushort ushort8;
typedef __attribute__((ext_vector_type(4))) float f32x4;

__device__ __forceinline__ ushort f2bf(float f) {
    union { float f; unsigned u; } v; v.f = f;
    unsigned u = v.u;
    unsigned r = (u + 0x7fffu + ((u >> 16) & 1u)) >> 16;  // RNE
    return (ushort)r;
}
__device__ __forceinline__ float bf2f(ushort h) {
    union { unsigned u; float f; } v; v.u = ((unsigned)h) << 16;
    return v.f;
}

#define ASYNC_COPY16(gsrc, ldst) \
    __builtin_amdgcn_global_load_lds((const __attribute__((address_space(1))) void*)(gsrc), \
                                     (__attribute__((address_space(3))) void*)(ldst), 16, 0, 0)

// ---------------------------------------------------------------------------
// fp32 -> bf16 conversion, 8 elements per thread
// ---------------------------------------------------------------------------
__global__ void convert_kernel(const float* __restrict__ in, ushort* __restrict__ out, int n8) {
    int i = blockIdx.x * blockDim.x + threadIdx.x;
    if (i >= n8) return;
    const float4* p = reinterpret_cast<const float4*>(in + (size_t)i * 8);
    float4 u = p[0], v = p[1];
    ushort4 o0 = { f2bf(u.x), f2bf(u.y), f2bf(u.z), f2bf(u.w) };
    ushort4 o1 = { f2bf(v.x), f2bf(v.y), f2bf(v.z), f2bf(v.w) };
    *reinterpret_cast<ushort4*>(out + (size_t)i * 8)     = o0;
    *reinterpret_cast<ushort4*>(out + (size_t)i * 8 + 4) = o1;
}

// ---------------------------------------------------------------------------
// Kernel 1: count in-degree per (batch, dst); 4 edges per thread via int4
// ---------------------------------------------------------------------------
__global__ void count_kernel(const int* __restrict__ edges, int* __restrict__ counts) {
    int idx = blockIdx.x * blockDim.x + threadIdx.x;   // 0 .. B*E/4-1
    int b = idx >> 14;                                 // E/4 = 16384 per batch
    int e4 = idx & 16383;
    int4 d = *reinterpret_cast<const int4*>(edges + (size_t)b * 2 * NEDGE + NEDGE + e4 * 4);
    int* cb = counts + b * NNODE;
    atomicAdd(&cb[d.x], 1);
    atomicAdd(&cb[d.y], 1);
    atomicAdd(&cb[d.z], 1);
    atomicAdd(&cb[d.w], 1);
}

// ---------------------------------------------------------------------------
// Kernel 2: per-batch exclusive scan of counts -> cursor
// ---------------------------------------------------------------------------
__global__ void scan_kernel(const int* __restrict__ counts, int* __restrict__ cursor) {
    __shared__ int tsums[256];
    int b = blockIdx.x;
    int t = threadIdx.x;
    const int base = b * NNODE;
    int local[8];
    int s = 0;
#pragma unroll
    for (int j = 0; j < 8; ++j) { local[j] = counts[base + t * 8 + j]; s += local[j]; }
    tsums[t] = s;
    __syncthreads();
    for (int off = 1; off < 256; off <<= 1) {
        int v = (t >= off) ? tsums[t - off] : 0;
        __syncthreads();
        tsums[t] += v;
        __syncthreads();
    }
    int run = (t == 0) ? 0 : tsums[t - 1];
#pragma unroll
    for (int j = 0; j < 8; ++j) {
        cursor[base + t * 8 + j] = run;
        run += local[j];
    }
}

// ---------------------------------------------------------------------------
// Kernel 3: fill CSR src-index lists; 4 edges per thread via int4
// ---------------------------------------------------------------------------
__global__ void fill_kernel(const int* __restrict__ edges,
                            int* __restrict__ cursor,
                            int* __restrict__ srcIdx) {
    int idx = blockIdx.x * blockDim.x + threadIdx.x;   // 0 .. B*E/4-1
    int b = idx >> 14;
    int e4 = idx & 16383;
    const int* eb = edges + (size_t)b * 2 * NEDGE;
    int4 s = *reinterpret_cast<const int4*>(eb + e4 * 4);
    int4 d = *reinterpret_cast<const int4*>(eb + NEDGE + e4 * 4);
    int* cb = cursor + b * NNODE;
    int* sb = srcIdx + (size_t)b * NEDGE;
    sb[atomicAdd(&cb[d.x], 1)] = s.x;
    sb[atomicAdd(&cb[d.y], 1)] = s.y;
    sb[atomicAdd(&cb[d.z], 1)] = s.z;
    sb[atomicAdd(&cb[d.w], 1)] = s.w;
}

// ---------------------------------------------------------------------------
// Kernel 4: pull-style neighbor mean, bf16 features, fp32 accumulate.
// One wave per node. Half-wave per edge: lanes 0-31 process even edges,
// lanes 32-63 odd edges; each lane owns 8 features (ushort8 = 16B loads).
// 8-edge unroll -> 4 independent 16B gathers in flight per lane.
// Final merge across halves via __shfl_xor(.,32).
// ---------------------------------------------------------------------------
__global__ __launch_bounds__(256) void aggregate_kernel(
        const ushort* __restrict__ Xbf,
        const int* __restrict__ srcIdx,
        const int* __restrict__ cursor,
        const int* __restrict__ counts,
        ushort* __restrict__ Gbf) {
    int bid = blockIdx.x;                     // 8192 blocks
    int blk = (bid & 7) * 1024 + (bid >> 3);  // XCD-contiguous remap (bijective)
    int wave = threadIdx.x >> 6;
    int lane = threadIdx.x & 63;
    int half = lane >> 5;                     // 0: even edges, 1: odd edges
    int f0 = (lane & 31) * 8;                 // 8 features per lane
    int node = blk * 4 + wave;                // 0 .. B*N-1
    int b = node >> 11;
    int deg = counts[node];
    int start = cursor[node] - deg;           // cursor is end-offset after fill
    const ushort* xb = Xbf + (size_t)b * NNODE * DIN;
    const int* sidx = srcIdx + (size_t)b * NEDGE + start;

    float acc[8] = {};
    int i = 0;
    for (; i + 8 <= deg; i += 8) {
        int s0 = sidx[i + 0 + half], s1 = sidx[i + 2 + half];
        int s2 = sidx[i + 4 + half], s3 = sidx[i + 6 + half];
        ushort8 v0 = *reinterpret_cast<const ushort8*>(xb + (size_t)s0 * DIN + f0);
        ushort8 v1 = *reinterpret_cast<const ushort8*>(xb + (size_t)s1 * DIN + f0);
        ushort8 v2 = *reinterpret_cast<const ushort8*>(xb + (size_t)s2 * DIN + f0);
        ushort8 v3 = *reinterpret_cast<const ushort8*>(xb + (size_t)s3 * DIN + f0);
#pragma unroll
        for (int j = 0; j < 8; ++j)
            acc[j] += (bf2f(v0[j]) + bf2f(v1[j])) + (bf2f(v2[j]) + bf2f(v3[j]));
    }
    for (; i + 2 <= deg; i += 2) {
        int s0 = sidx[i + half];
        ushort8 v0 = *reinterpret_cast<const ushort8*>(xb + (size_t)s0 * DIN + f0);
#pragma unroll
        for (int j = 0; j < 8; ++j) acc[j] += bf2f(v0[j]);
    }
    if (i < deg && half == 0) {
        int s0 = sidx[i];
        ushort8 v0 = *reinterpret_cast<const ushort8*>(xb + (size_t)s0 * DIN + f0);
#pragma unroll
        for (int j = 0; j < 8; ++j) acc[j] += bf2f(v0[j]);
    }
    // merge even/odd halves (lane l <-> l^32 hold same features)
#pragma unroll
    for (int j = 0; j < 8; ++j) acc[j] += __shfl_xor(acc[j], 32, 64);

    if (half == 0) {
        float sc = 1.0f / (float)max(deg, 1);
        ushort8 o;
#pragma unroll
        for (int j = 0; j < 8; ++j) o[j] = f2bf(acc[j] * sc);
        *reinterpret_cast<ushort8*>(Gbf + (size_t)node * DIN + f0) = o;
    }
}

// ---------------------------------------------------------------------------
// Kernel 5: bf16 MFMA GEMM, 128x128 tile, BK=32, double-buffered LDS with
// 2-phase pipeline (counted vmcnt, raw s_barrier). XCD-chunked swizzle pairs
// the two col-tiles sharing an A panel onto the same XCD.
// ---------------------------------------------------------------------------
__global__ __launch_bounds__(256) void gemm_kernel(
        const ushort* __restrict__ Xbf,
        const ushort* __restrict__ Gbf,
        const ushort* __restrict__ Wbf,
        const float* __restrict__ bias,
        float* __restrict__ out) {
    __shared__ ushort As[2][128 * 32];   // [buf][row*32 + k]
    __shared__ ushort Bs[2][128 * 32];
    const int tid = threadIdx.x;
    const int wid = tid >> 6, lane = tid & 63;

    // 512 blocks: xcd-chunked bijective swizzle, then pair-decode (x,y)
    int orig = blockIdx.x;
    int logical = (orig & 7) * 64 + (orig >> 3);   // same XCD -> 64 consecutive
    int bx = logical >> 1;                          // row tile 0..255
    int by = logical & 1;                           // col tile 0..1
    const int rowBase = bx * 128;
    const int colBase = by * 128;
    const int wm = wid >> 1, wn = wid & 1;

    f32x4 acc[4][4] = {};

    const int lr = lane >> 2;          // 0..15
    const int lk = (lane & 3) * 8;     // k element slot

    const ushort* Arow = Xbf + (size_t)rowBase * DIN;    // k0 < 256
    const ushort* Grow = Gbf + (size_t)rowBase * DIN;    // k0 >= 256
    const ushort* Brow = Wbf + (size_t)colBase * KDIM;
    const int r0 = wid * 16 + lr;

#define STAGE(k0, buf) do {                                                   \
        const ushort* Ab = ((k0) < DIN) ? (Arow + (k0)) : (Grow + ((k0) - DIN)); \
        const ushort* Bb = Brow + (k0);                                       \
        ASYNC_COPY16(Ab + (size_t)r0 * DIN + lk,          &As[buf][wid * 512]);       \
        ASYNC_COPY16(Ab + (size_t)(r0 + 64) * DIN + lk,   &As[buf][2048 + wid * 512]);\
        ASYNC_COPY16(Bb + (size_t)r0 * KDIM + lk,         &Bs[buf][wid * 512]);       \
        ASYNC_COPY16(Bb + (size_t)(r0 + 64) * KDIM + lk,  &Bs[buf][2048 + wid * 512]);\
    } while (0)

    STAGE(0, 0);
    int cur = 0;
    for (int t = 0; t < 16; ++t) {
        if (t < 15) {
            STAGE((t + 1) * 32, cur ^ 1);
            asm volatile("s_waitcnt vmcnt(4)" ::: "memory");  // cur tile landed
        } else {
            asm volatile("s_waitcnt vmcnt(0)" ::: "memory");
        }
        __builtin_amdgcn_s_barrier();

        short8 a[4], b[4];
#pragma unroll
        for (int m = 0; m < 4; ++m)
            a[m] = *reinterpret_cast<const short8*>(
                &As[cur][(wm * 64 + m * 16 + (lane & 15)) * 32 + (lane >> 4) * 8]);
#pragma unroll
        for (int n = 0; n < 4; ++n)
            b[n] = *reinterpret_cast<const short8*>(
                &Bs[cur][(wn * 64 + n * 16 + (lane & 15)) * 32 + (lane >> 4) * 8]);
#pragma unroll
        for (int m = 0; m < 4; ++m)
#pragma unroll
            for (int n = 0; n < 4; ++n)
                acc[m][n] = __builtin_amdgcn_mfma_f32_16x16x32_bf16(
                    a[m], b[n], acc[m][n], 0, 0, 0);
        __builtin_amdgcn_s_barrier();
        cur ^= 1;
    }
#undef STAGE

    // epilogue: C/D layout col=lane&15, row=(lane>>4)*4+reg
    const int cl = lane & 15, rq = lane >> 4;
#pragma unroll
    for (int n = 0; n < 4; ++n) {
        int col = colBase + wn * 64 + n * 16 + cl;
        float bv = bias[col];
#pragma unroll
        for (int m = 0; m < 4; ++m) {
            int r0o = rowBase + wm * 64 + m * 16 + rq * 4;
#pragma unroll
            for (int j = 0; j < 4; ++j)
                out[(size_t)(r0o + j) * DOUT + col] = acc[m][n][j] + bv;
        }
    }
}

// ---------------------------------------------------------------------------
extern "C" void kernel_launch(void* const* d_in, const int* in_sizes, int n_in,
                              void* d_out, int out_size, void* d_ws, size_t ws_size,
                              hipStream_t stream) {
    const float* X    = (const float*)d_in[0];   // (B, N, DIN)
    const int*   E    = (const int*)d_in[1];     // (B, 2, NEDGE) int32
    const float* W    = (const float*)d_in[2];   // (DOUT, KDIM)
    const float* bias = (const float*)d_in[3];   // (DOUT,)
    float* out = (float*)d_out;                  // (B, N, DOUT)

    char* ws = (char*)d_ws;
    ushort* Xbf = (ushort*)ws;                                  // 16.78 MB
    ushort* Gbf = Xbf + (size_t)BATCH * NNODE * DIN;            // 16.78 MB
    ushort* Wbf = Gbf + (size_t)BATCH * NNODE * DIN;            // 256 KB
    int* counts = (int*)(Wbf + (size_t)DOUT * KDIM);            // 128 KB
    int* cursor = counts + BATCH * NNODE;                       // 128 KB
    int* srcIdx = cursor + BATCH * NNODE;                       // 4 MB

    hipMemsetAsync(counts, 0, (size_t)BATCH * NNODE * sizeof(int), stream);

    convert_kernel<<<(BATCH * NNODE * DIN / 8) / 256, 256, 0, stream>>>(
        X, Xbf, BATCH * NNODE * DIN / 8);
    convert_kernel<<<(DOUT * KDIM / 8) / 256, 256, 0, stream>>>(
        W, Wbf, DOUT * KDIM / 8);

    const int totalE4 = BATCH * NEDGE / 4;       // 262144
    count_kernel<<<totalE4 / 256, 256, 0, stream>>>(E, counts);
    scan_kernel<<<BATCH, 256, 0, stream>>>(counts, cursor);
    fill_kernel<<<totalE4 / 256, 256, 0, stream>>>(E, cursor, srcIdx);

    aggregate_kernel<<<(BATCH * NNODE) / 4, 256, 0, stream>>>(
        Xbf, srcIdx, cursor, counts, Gbf);

    dim3 ggrid(512);
    gemm_kernel<<<ggrid, 256, 0, stream>>>(Xbf, Gbf, Wbf, bias, out);
}

// Round 4
// 132.098 us; speedup vs baseline: 2.4995x; 1.0774x over previous
//
#include <hip/hip_runtime.h>
#include <hip/hip_bf16.h>

#define BATCH 16
#define NNODE 2048
#define NEDGE 65536
#define DIN   256
#define DOUT  256
#define KDIM  512   // 2*DIN

typedef __attribute__((ext_vector_type(8))) short short8;
typedef __attribute__((ext_vector_type(8))) ushort ushort8;
typedef __attribute__((ext_vector_type(4))) float f32x4;

__device__ __forceinline__ ushort f2bf(float f) {
    union { float f; unsigned u; } v; v.f = f;
    unsigned u = v.u;
    unsigned r = (u + 0x7fffu + ((u >> 16) & 1u)) >> 16;  // RNE
    return (ushort)r;
}
__device__ __forceinline__ float bf2f(ushort h) {
    union { unsigned u; float f; } v; v.u = ((unsigned)h) << 16;
    return v.f;
}

#define ASYNC_COPY16(gsrc, ldst) \
    __builtin_amdgcn_global_load_lds((const __attribute__((address_space(1))) void*)(gsrc), \
                                     (__attribute__((address_space(3))) void*)(ldst), 16, 0, 0)

// ---------------------------------------------------------------------------
// Fused prep: blocks [0,1024) count in-degree (XCD-local per batch),
//             blocks [1024,5120) convert X fp32->bf16,
//             blocks [5120,5184) convert W fp32->bf16.
// XCD-local decode for count: batch = bid&15, chunk = bid>>4  ->  all 64
// blocks of batch b sit at bid ≡ b (mod 16) -> XCD b%8. counts atomics and
// edge reads stay in one XCD's L2.
// ---------------------------------------------------------------------------
__global__ __launch_bounds__(256) void fused_prep_kernel(
        const float* __restrict__ X, const float* __restrict__ W,
        const int* __restrict__ E, int* __restrict__ counts,
        ushort* __restrict__ Xbf, ushort* __restrict__ Wbf) {
    int bid = blockIdx.x;
    int tid = threadIdx.x;
    if (bid < 1024) {
        int b = bid & 15;
        int e4 = (bid >> 4) * 256 + tid;       // 0..16383
        int4 d = *reinterpret_cast<const int4*>(
            E + (size_t)b * 2 * NEDGE + NEDGE + e4 * 4);
        int* cb = counts + b * NNODE;
        atomicAdd(&cb[d.x], 1);
        atomicAdd(&cb[d.y], 1);
        atomicAdd(&cb[d.z], 1);
        atomicAdd(&cb[d.w], 1);
    } else if (bid < 5120) {
        size_t i = (size_t)(bid - 1024) * 256 + tid;
        const float4* p = reinterpret_cast<const float4*>(X + i * 8);
        float4 u = p[0], v = p[1];
        ushort4 o0 = { f2bf(u.x), f2bf(u.y), f2bf(u.z), f2bf(u.w) };
        ushort4 o1 = { f2bf(v.x), f2bf(v.y), f2bf(v.z), f2bf(v.w) };
        *reinterpret_cast<ushort4*>(Xbf + i * 8)     = o0;
        *reinterpret_cast<ushort4*>(Xbf + i * 8 + 4) = o1;
    } else {
        size_t i = (size_t)(bid - 5120) * 256 + tid;
        const float4* p = reinterpret_cast<const float4*>(W + i * 8);
        float4 u = p[0], v = p[1];
        ushort4 o0 = { f2bf(u.x), f2bf(u.y), f2bf(u.z), f2bf(u.w) };
        ushort4 o1 = { f2bf(v.x), f2bf(v.y), f2bf(v.z), f2bf(v.w) };
        *reinterpret_cast<ushort4*>(Wbf + i * 8)     = o0;
        *reinterpret_cast<ushort4*>(Wbf + i * 8 + 4) = o1;
    }
}

// ---------------------------------------------------------------------------
// Kernel 2: per-batch exclusive scan of counts -> cursor
// ---------------------------------------------------------------------------
__global__ void scan_kernel(const int* __restrict__ counts, int* __restrict__ cursor) {
    __shared__ int tsums[256];
    int b = blockIdx.x;
    int t = threadIdx.x;
    const int base = b * NNODE;
    int local[8];
    int s = 0;
#pragma unroll
    for (int j = 0; j < 8; ++j) { local[j] = counts[base + t * 8 + j]; s += local[j]; }
    tsums[t] = s;
    __syncthreads();
    for (int off = 1; off < 256; off <<= 1) {
        int v = (t >= off) ? tsums[t - off] : 0;
        __syncthreads();
        tsums[t] += v;
        __syncthreads();
    }
    int run = (t == 0) ? 0 : tsums[t - 1];
#pragma unroll
    for (int j = 0; j < 8; ++j) {
        cursor[base + t * 8 + j] = run;
        run += local[j];
    }
}

// ---------------------------------------------------------------------------
// Kernel 3: fill CSR src-index lists, XCD-local per batch (same decode as
// count): cursor atomics + srcIdx scatter stay within one XCD's L2 ->
// no cross-XCD partial-line writebacks.
// ---------------------------------------------------------------------------
__global__ __launch_bounds__(256) void fill_kernel(
        const int* __restrict__ edges,
        int* __restrict__ cursor,
        int* __restrict__ srcIdx) {
    int bid = blockIdx.x;                      // 1024 blocks
    int b = bid & 15;
    int e4 = (bid >> 4) * 256 + threadIdx.x;   // 0..16383
    const int* eb = edges + (size_t)b * 2 * NEDGE;
    int4 s = *reinterpret_cast<const int4*>(eb + e4 * 4);
    int4 d = *reinterpret_cast<const int4*>(eb + NEDGE + e4 * 4);
    int* cb = cursor + b * NNODE;
    int* sb = srcIdx + (size_t)b * NEDGE;
    sb[atomicAdd(&cb[d.x], 1)] = s.x;
    sb[atomicAdd(&cb[d.y], 1)] = s.y;
    sb[atomicAdd(&cb[d.z], 1)] = s.z;
    sb[atomicAdd(&cb[d.w], 1)] = s.w;
}

// ---------------------------------------------------------------------------
// Kernel 4: pull-style neighbor mean, bf16 features, fp32 accumulate.
// One wave per node; half-wave per edge; lane owns 8 features (16B loads);
// 8-edge unroll -> 4 independent gathers in flight. XCD swizzle: 2 batches
// per XCD so gathers hit XCD-local L2.
// ---------------------------------------------------------------------------
__global__ __launch_bounds__(256) void aggregate_kernel(
        const ushort* __restrict__ Xbf,
        const int* __restrict__ srcIdx,
        const int* __restrict__ cursor,
        const int* __restrict__ counts,
        ushort* __restrict__ Gbf) {
    int bid = blockIdx.x;                     // 8192 blocks
    int blk = (bid & 7) * 1024 + (bid >> 3);  // XCD-contiguous remap (bijective)
    int wave = threadIdx.x >> 6;
    int lane = threadIdx.x & 63;
    int half = lane >> 5;                     // 0: even edges, 1: odd edges
    int f0 = (lane & 31) * 8;                 // 8 features per lane
    int node = blk * 4 + wave;                // 0 .. B*N-1
    int b = node >> 11;
    int deg = counts[node];
    int start = cursor[node] - deg;           // cursor is end-offset after fill
    const ushort* xb = Xbf + (size_t)b * NNODE * DIN;
    const int* sidx = srcIdx + (size_t)b * NEDGE + start;

    float acc[8] = {};
    int i = 0;
    for (; i + 8 <= deg; i += 8) {
        int s0 = sidx[i + 0 + half], s1 = sidx[i + 2 + half];
        int s2 = sidx[i + 4 + half], s3 = sidx[i + 6 + half];
        ushort8 v0 = *reinterpret_cast<const ushort8*>(xb + (size_t)s0 * DIN + f0);
        ushort8 v1 = *reinterpret_cast<const ushort8*>(xb + (size_t)s1 * DIN + f0);
        ushort8 v2 = *reinterpret_cast<const ushort8*>(xb + (size_t)s2 * DIN + f0);
        ushort8 v3 = *reinterpret_cast<const ushort8*>(xb + (size_t)s3 * DIN + f0);
#pragma unroll
        for (int j = 0; j < 8; ++j)
            acc[j] += (bf2f(v0[j]) + bf2f(v1[j])) + (bf2f(v2[j]) + bf2f(v3[j]));
    }
    for (; i + 2 <= deg; i += 2) {
        int s0 = sidx[i + half];
        ushort8 v0 = *reinterpret_cast<const ushort8*>(xb + (size_t)s0 * DIN + f0);
#pragma unroll
        for (int j = 0; j < 8; ++j) acc[j] += bf2f(v0[j]);
    }
    if (i < deg && half == 0) {
        int s0 = sidx[i];
        ushort8 v0 = *reinterpret_cast<const ushort8*>(xb + (size_t)s0 * DIN + f0);
#pragma unroll
        for (int j = 0; j < 8; ++j) acc[j] += bf2f(v0[j]);
    }
#pragma unroll
    for (int j = 0; j < 8; ++j) acc[j] += __shfl_xor(acc[j], 32, 64);

    if (half == 0) {
        float sc = 1.0f / (float)max(deg, 1);
        ushort8 o;
#pragma unroll
        for (int j = 0; j < 8; ++j) o[j] = f2bf(acc[j] * sc);
        *reinterpret_cast<ushort8*>(Gbf + (size_t)node * DIN + f0) = o;
    }
}

// ---------------------------------------------------------------------------
// Kernel 5: bf16 MFMA GEMM, 128x128 tile, BK=32, double-buffered LDS with
// 2-phase pipeline (counted vmcnt, raw s_barrier). XCD-chunked swizzle.
// ---------------------------------------------------------------------------
__global__ __launch_bounds__(256) void gemm_kernel(
        const ushort* __restrict__ Xbf,
        const ushort* __restrict__ Gbf,
        const ushort* __restrict__ Wbf,
        const float* __restrict__ bias,
        float* __restrict__ out) {
    __shared__ ushort As[2][128 * 32];   // [buf][row*32 + k]
    __shared__ ushort Bs[2][128 * 32];
    const int tid = threadIdx.x;
    const int wid = tid >> 6, lane = tid & 63;

    int orig = blockIdx.x;
    int logical = (orig & 7) * 64 + (orig >> 3);
    int bx = logical >> 1;
    int by = logical & 1;
    const int rowBase = bx * 128;
    const int colBase = by * 128;
    const int wm = wid >> 1, wn = wid & 1;

    f32x4 acc[4][4] = {};

    const int lr = lane >> 2;
    const int lk = (lane & 3) * 8;

    const ushort* Arow = Xbf + (size_t)rowBase * DIN;
    const ushort* Grow = Gbf + (size_t)rowBase * DIN;
    const ushort* Brow = Wbf + (size_t)colBase * KDIM;
    const int r0 = wid * 16 + lr;

#define STAGE(k0, buf) do {                                                   \
        const ushort* Ab = ((k0) < DIN) ? (Arow + (k0)) : (Grow + ((k0) - DIN)); \
        const ushort* Bb = Brow + (k0);                                       \
        ASYNC_COPY16(Ab + (size_t)r0 * DIN + lk,          &As[buf][wid * 512]);       \
        ASYNC_COPY16(Ab + (size_t)(r0 + 64) * DIN + lk,   &As[buf][2048 + wid * 512]);\
        ASYNC_COPY16(Bb + (size_t)r0 * KDIM + lk,         &Bs[buf][wid * 512]);       \
        ASYNC_COPY16(Bb + (size_t)(r0 + 64) * KDIM + lk,  &Bs[buf][2048 + wid * 512]);\
    } while (0)

    STAGE(0, 0);
    int cur = 0;
    for (int t = 0; t < 16; ++t) {
        if (t < 15) {
            STAGE((t + 1) * 32, cur ^ 1);
            asm volatile("s_waitcnt vmcnt(4)" ::: "memory");
        } else {
            asm volatile("s_waitcnt vmcnt(0)" ::: "memory");
        }
        __builtin_amdgcn_s_barrier();

        short8 a[4], b[4];
#pragma unroll
        for (int m = 0; m < 4; ++m)
            a[m] = *reinterpret_cast<const short8*>(
                &As[cur][(wm * 64 + m * 16 + (lane & 15)) * 32 + (lane >> 4) * 8]);
#pragma unroll
        for (int n = 0; n < 4; ++n)
            b[n] = *reinterpret_cast<const short8*>(
                &Bs[cur][(wn * 64 + n * 16 + (lane & 15)) * 32 + (lane >> 4) * 8]);
#pragma unroll
        for (int m = 0; m < 4; ++m)
#pragma unroll
            for (int n = 0; n < 4; ++n)
                acc[m][n] = __builtin_amdgcn_mfma_f32_16x16x32_bf16(
                    a[m], b[n], acc[m][n], 0, 0, 0);
        __builtin_amdgcn_s_barrier();
        cur ^= 1;
    }
#undef STAGE

    const int cl = lane & 15, rq = lane >> 4;
#pragma unroll
    for (int n = 0; n < 4; ++n) {
        int col = colBase + wn * 64 + n * 16 + cl;
        float bv = bias[col];
#pragma unroll
        for (int m = 0; m < 4; ++m) {
            int r0o = rowBase + wm * 64 + m * 16 + rq * 4;
#pragma unroll
            for (int j = 0; j < 4; ++j)
                out[(size_t)(r0o + j) * DOUT + col] = acc[m][n][j] + bv;
        }
    }
}

// ---------------------------------------------------------------------------
extern "C" void kernel_launch(void* const* d_in, const int* in_sizes, int n_in,
                              void* d_out, int out_size, void* d_ws, size_t ws_size,
                              hipStream_t stream) {
    const float* X    = (const float*)d_in[0];   // (B, N, DIN)
    const int*   E    = (const int*)d_in[1];     // (B, 2, NEDGE) int32
    const float* W    = (const float*)d_in[2];   // (DOUT, KDIM)
    const float* bias = (const float*)d_in[3];   // (DOUT,)
    float* out = (float*)d_out;                  // (B, N, DOUT)

    char* ws = (char*)d_ws;
    ushort* Xbf = (ushort*)ws;                                  // 16.78 MB
    ushort* Gbf = Xbf + (size_t)BATCH * NNODE * DIN;            // 16.78 MB
    ushort* Wbf = Gbf + (size_t)BATCH * NNODE * DIN;            // 256 KB
    int* counts = (int*)(Wbf + (size_t)DOUT * KDIM);            // 128 KB
    int* cursor = counts + BATCH * NNODE;                       // 128 KB
    int* srcIdx = cursor + BATCH * NNODE;                       // 4 MB

    hipMemsetAsync(counts, 0, (size_t)BATCH * NNODE * sizeof(int), stream);

    // count (1024 blocks, XCD-local) + convert X (4096) + convert W (64)
    fused_prep_kernel<<<5184, 256, 0, stream>>>(X, W, E, counts, Xbf, Wbf);

    scan_kernel<<<BATCH, 256, 0, stream>>>(counts, cursor);
    fill_kernel<<<1024, 256, 0, stream>>>(E, cursor, srcIdx);

    aggregate_kernel<<<(BATCH * NNODE) / 4, 256, 0, stream>>>(
        Xbf, srcIdx, cursor, counts, Gbf);

    dim3 ggrid(512);
    gemm_kernel<<<ggrid, 256, 0, stream>>>(Xbf, Gbf, Wbf, bias, out);
}

// Round 5
// 97.910 us; speedup vs baseline: 3.3723x; 1.3492x over previous
//
#include <hip/hip_runtime.h>
#include <hip/hip_bf16.h>

#define BATCH 16
#define NNODE 2048
#define NEDGE 65536
#define DIN   256
#define DOUT  256
#define KDIM  512   // 2*DIN

typedef __attribute__((ext_vector_type(8))) short short8;
typedef __attribute__((ext_vector_type(8))) ushort ushort8;
typedef __attribute__((ext_vector_type(4))) float f32x4;

__device__ __forceinline__ ushort f2bf(float f) {
    union { float f; unsigned u; } v; v.f = f;
    unsigned u = v.u;
    unsigned r = (u + 0x7fffu + ((u >> 16) & 1u)) >> 16;  // RNE
    return (ushort)r;
}
__device__ __forceinline__ float bf2f(ushort h) {
    union { unsigned u; float f; } v; v.u = ((unsigned)h) << 16;
    return v.f;
}

#define ASYNC_COPY16(gsrc, ldst) \
    __builtin_amdgcn_global_load_lds((const __attribute__((address_space(1))) void*)(gsrc), \
                                     (__attribute__((address_space(3))) void*)(ldst), 16, 0, 0)

// ---------------------------------------------------------------------------
// Fused prep (1056 blocks x 1024 threads):
//   blocks [0,16):      per-batch LDS histogram of dst + LDS scan ->
//                       counts + cursor (exclusive offsets). No global
//                       atomics, no memset needed.
//   blocks [16,1040):   convert X fp32->bf16 (8 elems/thread)
//   blocks [1040,1056): convert W fp32->bf16
// ---------------------------------------------------------------------------
__global__ __launch_bounds__(1024) void prep_kernel(
        const float* __restrict__ X, const float* __restrict__ W,
        const int* __restrict__ E,
        int* __restrict__ counts, int* __restrict__ cursor,
        ushort* __restrict__ Xbf, ushort* __restrict__ Wbf) {
    int bid = blockIdx.x;
    int t = threadIdx.x;
    if (bid < 16) {
        __shared__ int hist[NNODE];
        __shared__ int tsum[1024];
        int b = bid;
        hist[t] = 0;
        hist[t + 1024] = 0;
        __syncthreads();
        const int4* dsts = reinterpret_cast<const int4*>(
            E + (size_t)b * 2 * NEDGE + NEDGE);
#pragma unroll
        for (int j = 0; j < 16; ++j) {
            int4 d = dsts[j * 1024 + t];
            atomicAdd(&hist[d.x], 1);
            atomicAdd(&hist[d.y], 1);
            atomicAdd(&hist[d.z], 1);
            atomicAdd(&hist[d.w], 1);
        }
        __syncthreads();
        int c0 = hist[2 * t], c1 = hist[2 * t + 1];
        tsum[t] = c0 + c1;
        __syncthreads();
        for (int off = 1; off < 1024; off <<= 1) {
            int v = (t >= off) ? tsum[t - off] : 0;
            __syncthreads();
            tsum[t] += v;
            __syncthreads();
        }
        int run = (t == 0) ? 0 : tsum[t - 1];
        int base = b * NNODE;
        counts[base + 2 * t]     = c0;
        counts[base + 2 * t + 1] = c1;
        cursor[base + 2 * t]     = run;
        cursor[base + 2 * t + 1] = run + c0;
    } else if (bid < 1040) {
        size_t i = (size_t)(bid - 16) * 1024 + t;
        const float4* p = reinterpret_cast<const float4*>(X + i * 8);
        float4 u = p[0], v = p[1];
        ushort4 o0 = { f2bf(u.x), f2bf(u.y), f2bf(u.z), f2bf(u.w) };
        ushort4 o1 = { f2bf(v.x), f2bf(v.y), f2bf(v.z), f2bf(v.w) };
        *reinterpret_cast<ushort4*>(Xbf + i * 8)     = o0;
        *reinterpret_cast<ushort4*>(Xbf + i * 8 + 4) = o1;
    } else {
        size_t i = (size_t)(bid - 1040) * 1024 + t;
        const float4* p = reinterpret_cast<const float4*>(W + i * 8);
        float4 u = p[0], v = p[1];
        ushort4 o0 = { f2bf(u.x), f2bf(u.y), f2bf(u.z), f2bf(u.w) };
        ushort4 o1 = { f2bf(v.x), f2bf(v.y), f2bf(v.z), f2bf(v.w) };
        *reinterpret_cast<ushort4*>(Wbf + i * 8)     = o0;
        *reinterpret_cast<ushort4*>(Wbf + i * 8 + 4) = o1;
    }
}

// ---------------------------------------------------------------------------
// fill CSR src-index lists, XCD-local per batch (batch = bid&15 -> all 64
// blocks of a batch on one XCD; cursor atomics + srcIdx scatter stay in one
// L2, no cross-XCD partial-line writebacks).
// NOTE: cursor ends as end-offsets (start = cursor - counts).
// ---------------------------------------------------------------------------
__global__ __launch_bounds__(256) void fill_kernel(
        const int* __restrict__ edges,
        int* __restrict__ cursor,
        int* __restrict__ srcIdx) {
    int bid = blockIdx.x;                      // 1024 blocks
    int b = bid & 15;
    int e4 = (bid >> 4) * 256 + threadIdx.x;   // 0..16383
    const int* eb = edges + (size_t)b * 2 * NEDGE;
    int4 s = *reinterpret_cast<const int4*>(eb + e4 * 4);
    int4 d = *reinterpret_cast<const int4*>(eb + NEDGE + e4 * 4);
    int* cb = cursor + b * NNODE;
    int* sb = srcIdx + (size_t)b * NEDGE;
    sb[atomicAdd(&cb[d.x], 1)] = s.x;
    sb[atomicAdd(&cb[d.y], 1)] = s.y;
    sb[atomicAdd(&cb[d.z], 1)] = s.z;
    sb[atomicAdd(&cb[d.w], 1)] = s.w;
}

// ---------------------------------------------------------------------------
// pull-style neighbor mean, bf16 features, fp32 accumulate. One wave per
// node; half-wave per edge; lane owns 8 features (16B loads); 8-edge unroll
// -> 4 independent gathers in flight. XCD swizzle: 2 batches per XCD.
// ---------------------------------------------------------------------------
__global__ __launch_bounds__(256) void aggregate_kernel(
        const ushort* __restrict__ Xbf,
        const int* __restrict__ srcIdx,
        const int* __restrict__ cursor,
        const int* __restrict__ counts,
        ushort* __restrict__ Gbf) {
    int bid = blockIdx.x;                     // 8192 blocks
    int blk = (bid & 7) * 1024 + (bid >> 3);  // XCD-contiguous remap (bijective)
    int wave = threadIdx.x >> 6;
    int lane = threadIdx.x & 63;
    int half = lane >> 5;                     // 0: even edges, 1: odd edges
    int f0 = (lane & 31) * 8;                 // 8 features per lane
    int node = blk * 4 + wave;                // 0 .. B*N-1
    int b = node >> 11;
    int deg = counts[node];
    int start = cursor[node] - deg;           // cursor is end-offset after fill
    const ushort* xb = Xbf + (size_t)b * NNODE * DIN;
    const int* sidx = srcIdx + (size_t)b * NEDGE + start;

    float acc[8] = {};
    int i = 0;
    for (; i + 8 <= deg; i += 8) {
        int s0 = sidx[i + 0 + half], s1 = sidx[i + 2 + half];
        int s2 = sidx[i + 4 + half], s3 = sidx[i + 6 + half];
        ushort8 v0 = *reinterpret_cast<const ushort8*>(xb + (size_t)s0 * DIN + f0);
        ushort8 v1 = *reinterpret_cast<const ushort8*>(xb + (size_t)s1 * DIN + f0);
        ushort8 v2 = *reinterpret_cast<const ushort8*>(xb + (size_t)s2 * DIN + f0);
        ushort8 v3 = *reinterpret_cast<const ushort8*>(xb + (size_t)s3 * DIN + f0);
#pragma unroll
        for (int j = 0; j < 8; ++j)
            acc[j] += (bf2f(v0[j]) + bf2f(v1[j])) + (bf2f(v2[j]) + bf2f(v3[j]));
    }
    for (; i + 2 <= deg; i += 2) {
        int s0 = sidx[i + half];
        ushort8 v0 = *reinterpret_cast<const ushort8*>(xb + (size_t)s0 * DIN + f0);
#pragma unroll
        for (int j = 0; j < 8; ++j) acc[j] += bf2f(v0[j]);
    }
    if (i < deg && half == 0) {
        int s0 = sidx[i];
        ushort8 v0 = *reinterpret_cast<const ushort8*>(xb + (size_t)s0 * DIN + f0);
#pragma unroll
        for (int j = 0; j < 8; ++j) acc[j] += bf2f(v0[j]);
    }
#pragma unroll
    for (int j = 0; j < 8; ++j) acc[j] += __shfl_xor(acc[j], 32, 64);

    if (half == 0) {
        float sc = 1.0f / (float)max(deg, 1);
        ushort8 o;
#pragma unroll
        for (int j = 0; j < 8; ++j) o[j] = f2bf(acc[j] * sc);
        *reinterpret_cast<ushort8*>(Gbf + (size_t)node * DIN + f0) = o;
    }
}

// ---------------------------------------------------------------------------
// bf16 MFMA GEMM, 128x128 tile, BK=32, double-buffered LDS, 2-phase pipeline
// (counted vmcnt, raw s_barrier). XCD-chunked swizzle.
// ---------------------------------------------------------------------------
__global__ __launch_bounds__(256) void gemm_kernel(
        const ushort* __restrict__ Xbf,
        const ushort* __restrict__ Gbf,
        const ushort* __restrict__ Wbf,
        const float* __restrict__ bias,
        float* __restrict__ out) {
    __shared__ ushort As[2][128 * 32];   // [buf][row*32 + k]
    __shared__ ushort Bs[2][128 * 32];
    const int tid = threadIdx.x;
    const int wid = tid >> 6, lane = tid & 63;

    int orig = blockIdx.x;
    int logical = (orig & 7) * 64 + (orig >> 3);
    int bx = logical >> 1;
    int by = logical & 1;
    const int rowBase = bx * 128;
    const int colBase = by * 128;
    const int wm = wid >> 1, wn = wid & 1;

    f32x4 acc[4][4] = {};

    const int lr = lane >> 2;
    const int lk = (lane & 3) * 8;

    const ushort* Arow = Xbf + (size_t)rowBase * DIN;
    const ushort* Grow = Gbf + (size_t)rowBase * DIN;
    const ushort* Brow = Wbf + (size_t)colBase * KDIM;
    const int r0 = wid * 16 + lr;

#define STAGE(k0, buf) do {                                                   \
        const ushort* Ab = ((k0) < DIN) ? (Arow + (k0)) : (Grow + ((k0) - DIN)); \
        const ushort* Bb = Brow + (k0);                                       \
        ASYNC_COPY16(Ab + (size_t)r0 * DIN + lk,          &As[buf][wid * 512]);       \
        ASYNC_COPY16(Ab + (size_t)(r0 + 64) * DIN + lk,   &As[buf][2048 + wid * 512]);\
        ASYNC_COPY16(Bb + (size_t)r0 * KDIM + lk,         &Bs[buf][wid * 512]);       \
        ASYNC_COPY16(Bb + (size_t)(r0 + 64) * KDIM + lk,  &Bs[buf][2048 + wid * 512]);\
    } while (0)

    STAGE(0, 0);
    int cur = 0;
    for (int t = 0; t < 16; ++t) {
        if (t < 15) {
            STAGE((t + 1) * 32, cur ^ 1);
            asm volatile("s_waitcnt vmcnt(4)" ::: "memory");
        } else {
            asm volatile("s_waitcnt vmcnt(0)" ::: "memory");
        }
        __builtin_amdgcn_s_barrier();

        short8 a[4], b[4];
#pragma unroll
        for (int m = 0; m < 4; ++m)
            a[m] = *reinterpret_cast<const short8*>(
                &As[cur][(wm * 64 + m * 16 + (lane & 15)) * 32 + (lane >> 4) * 8]);
#pragma unroll
        for (int n = 0; n < 4; ++n)
            b[n] = *reinterpret_cast<const short8*>(
                &Bs[cur][(wn * 64 + n * 16 + (lane & 15)) * 32 + (lane >> 4) * 8]);
#pragma unroll
        for (int m = 0; m < 4; ++m)
#pragma unroll
            for (int n = 0; n < 4; ++n)
                acc[m][n] = __builtin_amdgcn_mfma_f32_16x16x32_bf16(
                    a[m], b[n], acc[m][n], 0, 0, 0);
        __builtin_amdgcn_s_barrier();
        cur ^= 1;
    }
#undef STAGE

    const int cl = lane & 15, rq = lane >> 4;
#pragma unroll
    for (int n = 0; n < 4; ++n) {
        int col = colBase + wn * 64 + n * 16 + cl;
        float bv = bias[col];
#pragma unroll
        for (int m = 0; m < 4; ++m) {
            int r0o = rowBase + wm * 64 + m * 16 + rq * 4;
#pragma unroll
            for (int j = 0; j < 4; ++j)
                out[(size_t)(r0o + j) * DOUT + col] = acc[m][n][j] + bv;
        }
    }
}

// ---------------------------------------------------------------------------
extern "C" void kernel_launch(void* const* d_in, const int* in_sizes, int n_in,
                              void* d_out, int out_size, void* d_ws, size_t ws_size,
                              hipStream_t stream) {
    const float* X    = (const float*)d_in[0];   // (B, N, DIN)
    const int*   E    = (const int*)d_in[1];     // (B, 2, NEDGE) int32
    const float* W    = (const float*)d_in[2];   // (DOUT, KDIM)
    const float* bias = (const float*)d_in[3];   // (DOUT,)
    float* out = (float*)d_out;                  // (B, N, DOUT)

    char* ws = (char*)d_ws;
    ushort* Xbf = (ushort*)ws;                                  // 16.78 MB
    ushort* Gbf = Xbf + (size_t)BATCH * NNODE * DIN;            // 16.78 MB
    ushort* Wbf = Gbf + (size_t)BATCH * NNODE * DIN;            // 256 KB
    int* counts = (int*)(Wbf + (size_t)DOUT * KDIM);            // 128 KB
    int* cursor = counts + BATCH * NNODE;                       // 128 KB
    int* srcIdx = cursor + BATCH * NNODE;                       // 4 MB

    // hist+scan (16 blocks) + convert X (1024) + convert W (16); no memset
    prep_kernel<<<1056, 1024, 0, stream>>>(X, W, E, counts, cursor, Xbf, Wbf);

    fill_kernel<<<1024, 256, 0, stream>>>(E, cursor, srcIdx);

    aggregate_kernel<<<(BATCH * NNODE) / 4, 256, 0, stream>>>(
        Xbf, srcIdx, cursor, counts, Gbf);

    dim3 ggrid(512);
    gemm_kernel<<<ggrid, 256, 0, stream>>>(Xbf, Gbf, Wbf, bias, out);
}